// Round 12
// baseline (225.080 us; speedup 1.0000x reference)
//
#include <hip/hip_runtime.h>
#include <hip/hip_bf16.h>
#include <math.h>
#include <stdint.h>

#define VV 20000
#define LL 128
#define DD 256
#define DEMO_ 70
#define HID_ 1024
#define NN 2048

typedef __attribute__((ext_vector_type(8))) short short8;
typedef __attribute__((ext_vector_type(4))) float f32x4;

// ---- bf16 helpers ----
__device__ __forceinline__ float bf2f(uint32_t u) {
    union { uint32_t u; float f; } c; c.u = u << 16; return c.f;
}
__device__ __forceinline__ uint32_t f2bf(float f) {
    union { float f; uint32_t u; } c; c.f = f;
    return (c.u + 0x7fffu + ((c.u >> 16) & 1u)) >> 16;   // RNE
}

// swizzled halfword offset inside a [128][256] bf16 LDS tile
__device__ __forceinline__ int sw_off(int row, int col) {
    return (row << 8) + ((((col >> 3) ^ (row & 7)) << 3) | (col & 7));
}

// ---- fused pre-kernel (R7/R10-verified) ----
__global__ __launch_bounds__(256) void k_pre(
    const float* __restrict__ Wq, const float* __restrict__ Wk,
    const float* __restrict__ Wv, const float* __restrict__ W1,
    const float* __restrict__ ca, const float* __restrict__ cp,
    const int* __restrict__ lens,
    unsigned short* __restrict__ Mxf, unsigned short* __restrict__ W1f,
    int* __restrict__ order, float* __restrict__ z,
    int* __restrict__ tickets, float* __restrict__ out)
{
    __shared__ float sm[DD];
    __shared__ float wvs[8][DD];
    __shared__ int cnt[9], off[9], cur[9];
    const int b = blockIdx.x, t = threadIdx.x;

    if (b < 256) {
        int e = b;
        sm[t] = Wq[(size_t)e * DD + t];
        __syncthreads();
        const float4* wk4 = (const float4*)(Wk + (size_t)t * DD);
        const float4* wq4 = (const float4*)sm;
        float4 acc = make_float4(0.f, 0.f, 0.f, 0.f);
        #pragma unroll 8
        for (int c = 0; c < DD / 4; ++c) {
            float4 a = wq4[c]; float4 bb = wk4[c];
            acc.x += a.x * bb.x; acc.y += a.y * bb.y;
            acc.z += a.z * bb.z; acc.w += a.w * bb.w;
        }
        float val = acc.x + acc.y + acc.z + acc.w;
        int frag = (e >> 4) * 8 + (t >> 5);
        int pos  = (((t >> 3) & 3) * 16 + (e & 15)) * 8 + (t & 7);
        Mxf[(size_t)frag * 512 + pos] = (unsigned short)f2bf(val);
    } else if (b < 384) {
        int f = b - 256, kg = f >> 2, hh = f & 3;
        #pragma unroll
        for (int r = 0; r < 8; ++r)
            wvs[r][t] = Wv[(size_t)(kg * 8 + r) * DD + t];
        __syncthreads();
        int h = hh * 256 + t;
        float acc[8];
        #pragma unroll
        for (int r = 0; r < 8; ++r) acc[r] = 0.f;
        #pragma unroll 4
        for (int n = 0; n < DD; ++n) {
            float a = W1[(size_t)(DEMO_ + n) * HID_ + h];
            #pragma unroll
            for (int r = 0; r < 8; ++r) acc[r] += wvs[r][n] * a;
        }
        #pragma unroll
        for (int r = 0; r < 8; ++r) {
            int k = DEMO_ + kg * 8 + r;
            int frag = (h >> 4) * 11 + (k >> 5);
            int pos  = (((k >> 3) & 3) * 16 + (h & 15)) * 8 + (k & 7);
            W1f[(size_t)frag * 512 + pos] = (unsigned short)f2bf(acc[r]);
        }
    } else if (b < 416) {
        int g = b - 384;
        for (int idx = g * 256 + t; idx < 96 * 1024; idx += 32 * 256) {
            int kk = idx >> 10, h = idx & 1023;
            int k = kk < DEMO_ ? kk : kk + 256;
            float val = kk < DEMO_ ? W1[(size_t)kk * HID_ + h] : 0.f;
            int frag = (h >> 4) * 11 + (k >> 5);
            int pos  = (((k >> 3) & 3) * 16 + (h & 15)) * 8 + (k & 7);
            W1f[(size_t)frag * 512 + pos] = (unsigned short)f2bf(val);
        }
    } else {
        for (int i = t; i < NN; i += 256) z[i] = 0.f;
        if (t < 128) tickets[t] = 0;
        if (t < 9) cnt[t] = 0;
        __syncthreads();
        for (int i = t; i < NN; i += 256)
            atomicAdd(&cnt[(lens[i] + 15) >> 4], 1);
        __syncthreads();
        if (t == 0) {
            int acc = 0;
            for (int k = 8; k >= 1; --k) { off[k] = acc; acc += cnt[k]; cur[k] = off[k]; }
            out[0] = ca[0] * ca[0] + cp[0] * cp[0];
        }
        __syncthreads();
        for (int i = t; i < NN; i += 256) {
            int key = (lens[i] + 15) >> 4;
            int pos = atomicAdd(&cur[key], 1);
            order[pos] = i;
        }
    }
}

// ---- kernel 2: per-sample attention+pooling. Dual-path phase C/D ----
__global__ __launch_bounds__(512, 4) void k_main(
    const float* __restrict__ E,
    const float* __restrict__ ht,  const float* __restrict__ evt_t,
    const int* __restrict__ codes, const int* __restrict__ lens,
    const float* __restrict__ ca_p, const float* __restrict__ cp_p,
    const unsigned short* __restrict__ Mxf,
    const int* __restrict__ order,
    unsigned short* __restrict__ Rbf)
{
    __shared__ __align__(16) unsigned short emb_u[LL * DD];   // 64 KB; H overwrites in place
    __shared__ float times_s[LL];
    __shared__ int   codes_s[LL];
    __shared__ float w_s[LL];
    __shared__ float apart[8][LL];      // zero-inited; summed over all 8
    __shared__ float rp_part[8][DD];    // zero-inited; summed over all 8
    __shared__ float asum[LL];
    __shared__ float psum[8][16];       // partial rowsums exchange (wpt>1 path)

    const int n = order[blockIdx.x];
    const int tid = threadIdx.x, wv = tid >> 6, ln = tid & 63;
    const int q = ln >> 4, m = ln & 15;
    const int len = lens[n];
    const int it_n = (len + 15) >> 4;
    const float ca = ca_p[0], cp = cp_p[0];
    const float evt = evt_t[n];

    // waves-per-tile: it_n 1->8, 2->4, 3/4->2, >=5->1
    const int wsh = (it_n <= 1) ? 3 : (it_n == 2) ? 2 : (it_n <= 4) ? 1 : 0;
    const int wpt = 1 << wsh;
    const int tt = wv >> wsh, ss = wv & (wpt - 1);
    const bool act = tt < it_n;

    // ---- preload B-frags for phase B (in flight across gather)
    short8 bB[2][8];
    #pragma unroll
    for (int nt = 0; nt < 2; ++nt)
        #pragma unroll
        for (int kk = 0; kk < 8; ++kk)
            bB[nt][kk] = *(const short8*)(Mxf + (size_t)((wv * 2 + nt) * 8 + kk) * 512 + ln * 8);

    // ---- zero accumulation buffers
    ((float*)apart)[tid]          = 0.f;
    ((float*)apart)[tid + 512]    = 0.f;
    ((float*)rp_part)[tid]        = 0.f;
    ((float*)rp_part)[tid + 512]  = 0.f;
    ((float*)rp_part)[tid + 1024] = 0.f;
    ((float*)rp_part)[tid + 1536] = 0.f;

    // ---- stage times/codes; pooling weights (wave 0)
    if (tid < LL) {
        bool v = tid < len;
        times_s[tid] = v ? ht[(size_t)n * LL + tid] : 0.f;
        codes_s[tid] = v ? codes[(size_t)n * LL + tid] : 0;
    }
    if (wv == 0) {
        float t0 = (ln      < len) ? ht[(size_t)n * LL + ln]      : 0.f;
        float t1 = (ln + 64 < len) ? ht[(size_t)n * LL + ln + 64] : 0.f;
        float e0 = (ln      < len) ? __expf(cp * (t0 - evt)) : 0.f;
        float e1 = (ln + 64 < len) ? __expf(cp * (t1 - evt)) : 0.f;
        float smm = e0 + e1;
        for (int o = 32; o; o >>= 1) smm += __shfl_xor(smm, o, 64);
        float inv = 1.f / smm;
        if (ln      < len) w_s[ln]      = e0 * inv;
        if (ln + 64 < len) w_s[ln + 64] = e1 * inv;
    }
    __syncthreads();

    // ---- gather E rows -> swizzled bf16 LDS, 4 rows in flight per wave
    for (int l0 = wv; l0 < len; l0 += 32) {
        float4 v[4];
        #pragma unroll
        for (int u = 0; u < 4; ++u) {
            int l = l0 + u * 8;
            if (l < len)
                v[u] = ((const float4*)(E + (size_t)codes_s[l] * DD))[ln];
        }
        #pragma unroll
        for (int u = 0; u < 4; ++u) {
            int l = l0 + u * 8;
            if (l < len)
                *(uint2*)&emb_u[sw_off(l, 4 * ln)] =
                    make_uint2(f2bf(v[u].x) | (f2bf(v[u].y) << 16),
                               f2bf(v[u].z) | (f2bf(v[u].w) << 16));
        }
    }
    __syncthreads();

    // ---- phase B: H = emb @ Mx^T, overwriting emb tile-by-tile
    short8 aC[8];                        // cached A-frags for row tile tt
    for (int it = 0; it < it_n; ++it) {
        f32x4 h0 = (f32x4)0.f, h1 = (f32x4)0.f;
        #pragma unroll
        for (int kk = 0; kk < 8; ++kk) {
            short8 af = *(const short8*)&emb_u[sw_off(it * 16 + m, kk * 32 + q * 8)];
            if (it == tt) aC[kk] = af;   // wave-uniform
            h0 = __builtin_amdgcn_mfma_f32_16x16x32_bf16(af, bB[0][kk], h0, 0, 0, 0);
            h1 = __builtin_amdgcn_mfma_f32_16x16x32_bf16(af, bB[1][kk], h1, 0, 0, 0);
        }
        __syncthreads();
        #pragma unroll
        for (int r = 0; r < 4; ++r) {
            int row = it * 16 + q * 4 + r;
            emb_u[sw_off(row, wv * 32 + m)]      = (unsigned short)f2bf(h0[r]);
            emb_u[sw_off(row, wv * 32 + 16 + m)] = (unsigned short)f2bf(h1[r]);
        }
    }
    __syncthreads();                     // H fully materialized

    if (wpt == 1) {
        // ======== R10 path (it_n >= 5): barrier-free sac live range ========
        if (wv < it_n) {
            f32x4 sac[8];
            #pragma unroll
            for (int jt = 0; jt < 8; ++jt) sac[jt] = (f32x4)0.f;
            for (int jt = 0; jt < it_n; ++jt) {
                #pragma unroll
                for (int kk = 0; kk < 8; ++kk) {
                    short8 bH = *(const short8*)&emb_u[sw_off(jt * 16 + m, kk * 32 + q * 8)];
                    sac[jt] = __builtin_amdgcn_mfma_f32_16x16x32_bf16(aC[kk], bH, sac[jt], 0, 0, 0);
                }
            }
            int i_base = wv * 16 + q * 4;
            float ti[4]; bool vR[4]; float rowsum[4];
            #pragma unroll
            for (int r = 0; r < 4; ++r) {
                vR[r] = (i_base + r) < len;
                ti[r] = times_s[i_base + r];
                rowsum[r] = 0.f;
            }
            for (int jt = 0; jt < it_n; ++jt) {
                int jcol = jt * 16 + m;
                bool vC = jcol < len;
                float tj = times_s[jcol];
                #pragma unroll
                for (int r = 0; r < 4; ++r) {
                    float arg = sac[jt][r] * 0.0625f - ca * fabsf(ti[r] - tj);
                    float p = (vR[r] && vC) ? __expf(arg) : 0.f;
                    sac[jt][r] = p;
                    rowsum[r] += p;
                }
            }
            #pragma unroll
            for (int r = 0; r < 4; ++r) {
                float s = rowsum[r];
                s += __shfl_xor(s, 1, 64); s += __shfl_xor(s, 2, 64);
                s += __shfl_xor(s, 4, 64); s += __shfl_xor(s, 8, 64);
                rowsum[r] = s;
            }
            float sc[4];
            #pragma unroll
            for (int r = 0; r < 4; ++r)
                sc[r] = (vR[r] && rowsum[r] > 0.f) ? w_s[i_base + r] / rowsum[r] : 0.f;
            for (int jt = 0; jt < it_n; ++jt) {
                float v = sc[0] * sac[jt][0] + sc[1] * sac[jt][1]
                        + sc[2] * sac[jt][2] + sc[3] * sac[jt][3];
                v += __shfl_xor(v, 16, 64);
                v += __shfl_xor(v, 32, 64);
                if (q == 0) apart[wv][jt * 16 + m] = v;
            }
        }
        __syncthreads();

        if (tid < LL) {
            float s = 0.f;
            #pragma unroll
            for (int r = 0; r < 8; ++r) s += apart[r][tid];
            asum[tid] = s;
        }
        __syncthreads();

        // phase D: wave wv owns all 8 kk for its tile
        if (wv < it_n) {
            float aw = asum[wv * 16 + m];
            #pragma unroll
            for (int kk = 0; kk < 8; ++kk) {
                float v[8];
                #pragma unroll
                for (int j = 0; j < 8; ++j)
                    v[j] = aw * bf2f((uint32_t)(unsigned short)aC[kk][j]);
                #pragma unroll
                for (int o = 1; o <= 8; o <<= 1)
                    #pragma unroll
                    for (int j = 0; j < 8; ++j)
                        v[j] += __shfl_xor(v[j], o, 64);
                if (m < 8)
                    rp_part[wv][kk * 32 + q * 8 + m] = v[m];
            }
        }
    } else {
        // ======== shared path (it_n <= 4): wpt waves per tile ========
        f32x4 sac[4];                    // <= 4 tiles per wave on this path
        #pragma unroll
        for (int j2 = 0; j2 < 4; ++j2) sac[j2] = (f32x4)0.f;
        int i_base = tt * 16 + q * 4;
        float ti[4]; bool vR[4]; float rowsum[4];
        #pragma unroll
        for (int r = 0; r < 4; ++r) rowsum[r] = 0.f;

        if (act) {
            #pragma unroll
            for (int j2 = 0; j2 < 4; ++j2) {
                int jt = ss + j2 * wpt;
                if (jt < it_n) {
                    #pragma unroll
                    for (int kk = 0; kk < 8; ++kk) {
                        short8 bH = *(const short8*)&emb_u[sw_off(jt * 16 + m, kk * 32 + q * 8)];
                        sac[j2] = __builtin_amdgcn_mfma_f32_16x16x32_bf16(aC[kk], bH, sac[j2], 0, 0, 0);
                    }
                }
            }
            #pragma unroll
            for (int r = 0; r < 4; ++r) {
                vR[r] = (i_base + r) < len;
                ti[r] = times_s[i_base + r];
            }
            #pragma unroll
            for (int j2 = 0; j2 < 4; ++j2) {
                int jt = ss + j2 * wpt;
                if (jt < it_n) {
                    int jcol = jt * 16 + m;
                    bool vC = jcol < len;
                    float tj = times_s[jcol];
                    #pragma unroll
                    for (int r = 0; r < 4; ++r) {
                        float arg = sac[j2][r] * 0.0625f - ca * fabsf(ti[r] - tj);
                        float p = (vR[r] && vC) ? __expf(arg) : 0.f;
                        sac[j2][r] = p;
                        rowsum[r] += p;
                    }
                }
            }
            #pragma unroll
            for (int r = 0; r < 4; ++r) {
                float s = rowsum[r];
                s += __shfl_xor(s, 1, 64); s += __shfl_xor(s, 2, 64);
                s += __shfl_xor(s, 4, 64); s += __shfl_xor(s, 8, 64);
                rowsum[r] = s;
            }
            if (m == 0) {
                #pragma unroll
                for (int r = 0; r < 4; ++r) psum[wv][q * 4 + r] = rowsum[r];
            }
        }
        __syncthreads();

        if (act) {
            float sc[4];
            #pragma unroll
            for (int r = 0; r < 4; ++r) {
                float tot = 0.f;
                for (int s2 = 0; s2 < wpt; ++s2) tot += psum[tt * wpt + s2][q * 4 + r];
                sc[r] = (vR[r] && tot > 0.f) ? w_s[i_base + r] / tot : 0.f;
            }
            #pragma unroll
            for (int j2 = 0; j2 < 4; ++j2) {
                int jt = ss + j2 * wpt;
                if (jt < it_n) {
                    float v = sc[0] * sac[j2][0] + sc[1] * sac[j2][1]
                            + sc[2] * sac[j2][2] + sc[3] * sac[j2][3];
                    v += __shfl_xor(v, 16, 64);
                    v += __shfl_xor(v, 32, 64);
                    if (q == 0) apart[wv][jt * 16 + m] = v;
                }
            }
        }
        __syncthreads();

        if (tid < LL) {
            float s = 0.f;
            #pragma unroll
            for (int r = 0; r < 8; ++r) s += apart[r][tid];
            asum[tid] = s;
        }
        __syncthreads();

        // phase D: wave ss takes contiguous kk range (8/wpt each)
        if (act) {
            float aw = asum[tt * 16 + m];
            int kcnt = 8 >> wsh;
            int kk0 = ss * kcnt, kk1 = kk0 + kcnt;
            #pragma unroll
            for (int kk = 0; kk < 8; ++kk) {
                if (kk >= kk0 && kk < kk1) {
                    float v[8];
                    #pragma unroll
                    for (int j = 0; j < 8; ++j)
                        v[j] = aw * bf2f((uint32_t)(unsigned short)aC[kk][j]);
                    #pragma unroll
                    for (int o = 1; o <= 8; o <<= 1)
                        #pragma unroll
                        for (int j = 0; j < 8; ++j)
                            v[j] += __shfl_xor(v[j], o, 64);
                    if (m < 8)
                        rp_part[wv][kk * 32 + q * 8 + m] = v[m];
                }
            }
        }
    }
    __syncthreads();
    if (tid < DD) {
        float r = 0.f;
        #pragma unroll
        for (int t2 = 0; t2 < 8; ++t2) r += rp_part[t2][tid];
        Rbf[(size_t)n * DD + tid] = (unsigned short)f2bf(r);
    }
}

// ---- kernel 3: batched MLP partial-z + last-block BCE (R10-verified) ----
__global__ __launch_bounds__(256) void k_mlp(
    const float* __restrict__ demo, const float* __restrict__ labels,
    const float* __restrict__ b1,   const float* __restrict__ W2,
    const float* __restrict__ b2,
    const unsigned short* __restrict__ Rbf,
    const unsigned short* __restrict__ W1f,
    float* __restrict__ z, int* __restrict__ tickets,
    float* __restrict__ out)
{
    __shared__ __align__(16) unsigned short xs[16][360];
    __shared__ float W2s[256];
    __shared__ float b1s[256];
    __shared__ float wred[4][16];
    __shared__ int   lastflag;

    const int tid = threadIdx.x, wv = tid >> 6, ln = tid & 63;
    const int q = ln >> 4, m = ln & 15;
    const int sg = blockIdx.x;
    const int s0 = sg * 16;
    const int by = blockIdx.y;
    const int hbase = by * 256;

    W2s[tid] = W2[hbase + tid];
    b1s[tid] = b1[hbase + tid];
    {
        int sh = tid >> 6, lane = tid & 63;
        for (int s = sh; s < 16; s += 4) {
            int n_s = s0 + s;
            const uint32_t* rsrc = (const uint32_t*)(Rbf + (size_t)n_s * DD);
            ((uint32_t*)&xs[s][DEMO_])[lane]      = rsrc[lane];
            ((uint32_t*)&xs[s][DEMO_])[lane + 64] = rsrc[lane + 64];
            if (lane < 35) {
                float2 d = ((const float2*)(demo + (size_t)n_s * DEMO_))[lane];
                xs[s][2 * lane]     = (unsigned short)f2bf(d.x);
                xs[s][2 * lane + 1] = (unsigned short)f2bf(d.y);
            }
            if (lane < 17) ((uint32_t*)&xs[s][326])[lane] = 0;
        }
    }
    __syncthreads();

    f32x4 cacc[4];
    #pragma unroll
    for (int ntl = 0; ntl < 4; ++ntl) cacc[ntl] = (f32x4)0.f;

    for (int kk = 0; kk < 11; ++kk) {
        short8 af = *(const short8*)&xs[m][kk * 32 + q * 8];
        #pragma unroll
        for (int ntl = 0; ntl < 4; ++ntl) {
            int frag = (by * 16 + wv * 4 + ntl) * 11 + kk;
            short8 bfd = *(const short8*)(W1f + (size_t)frag * 512 + ln * 8);
            cacc[ntl] = __builtin_amdgcn_mfma_f32_16x16x32_bf16(af, bfd, cacc[ntl], 0, 0, 0);
        }
    }

    float ls0 = 0.f, ls1 = 0.f, ls2 = 0.f, ls3 = 0.f;
    #pragma unroll
    for (int ntl = 0; ntl < 4; ++ntl) {
        int hl = wv * 64 + ntl * 16 + m;
        float bb = b1s[hl], w2v = W2s[hl];
        ls0 += fmaxf(cacc[ntl][0] + bb, 0.f) * w2v;
        ls1 += fmaxf(cacc[ntl][1] + bb, 0.f) * w2v;
        ls2 += fmaxf(cacc[ntl][2] + bb, 0.f) * w2v;
        ls3 += fmaxf(cacc[ntl][3] + bb, 0.f) * w2v;
    }
    #pragma unroll
    for (int o = 1; o <= 8; o <<= 1) {
        ls0 += __shfl_xor(ls0, o, 64); ls1 += __shfl_xor(ls1, o, 64);
        ls2 += __shfl_xor(ls2, o, 64); ls3 += __shfl_xor(ls3, o, 64);
    }
    if (m == 0) {
        wred[wv][q * 4 + 0] = ls0; wred[wv][q * 4 + 1] = ls1;
        wred[wv][q * 4 + 2] = ls2; wred[wv][q * 4 + 3] = ls3;
    }
    __syncthreads();
    if (tid < 16)
        atomicAdd(&z[s0 + tid], wred[0][tid] + wred[1][tid] + wred[2][tid] + wred[3][tid]);
    __syncthreads();

    if (tid == 0) {
        __threadfence();
        int ticket = atomicAdd(&tickets[sg], 1);
        lastflag = (ticket == 3);
    }
    __syncthreads();
    if (lastflag && wv == 0) {
        float loss = 0.f;
        if (ln < 16) {
            float zz = atomicAdd(&z[s0 + ln], 0.f) + b2[0];   // device-scope read
            float y = labels[s0 + ln];
            float lg = log1pf(__expf(-fabsf(zz)));
            loss = 2.f * y * (fmaxf(-zz, 0.f) + lg)
                 + (1.f - y) * (fmaxf(zz, 0.f) + lg);
        }
        #pragma unroll
        for (int o = 1; o <= 8; o <<= 1) loss += __shfl_xor(loss, o, 64);
        if (ln == 0) atomicAdd(out, loss * (1.f / (float)NN));
    }
}

extern "C" void kernel_launch(void* const* d_in, const int* in_sizes, int n_in,
                              void* d_out, int out_size, void* d_ws, size_t ws_size,
                              hipStream_t stream) {
    const float* E      = (const float*)d_in[0];
    const float* Wq     = (const float*)d_in[1];
    const float* Wk     = (const float*)d_in[2];
    const float* Wv     = (const float*)d_in[3];
    const float* ca     = (const float*)d_in[4];
    const float* cp     = (const float*)d_in[5];
    const float* W1     = (const float*)d_in[6];
    const float* b1     = (const float*)d_in[7];
    const float* W2     = (const float*)d_in[8];
    const float* b2     = (const float*)d_in[9];
    const float* demo   = (const float*)d_in[10];
    const float* ht     = (const float*)d_in[11];
    const float* evt    = (const float*)d_in[12];
    const float* labels = (const float*)d_in[13];
    const int*   codes  = (const int*)d_in[14];
    const int*   lens   = (const int*)d_in[15];
    float* out = (float*)d_out;

    unsigned short* Mxf = (unsigned short*)d_ws;                           // 128 KB
    unsigned short* W1f = (unsigned short*)((char*)d_ws + 131072);         // 704 KB
    unsigned short* Rbf = (unsigned short*)((char*)d_ws + 851968);         // 1 MB
    float*          zar = (float*)((char*)d_ws + 1900544);                 // 8 KB
    int*            ord = (int*)((char*)d_ws + 1908736);                   // 8 KB
    int*            tks = (int*)((char*)d_ws + 1916928);                   // 512 B

    hipLaunchKernelGGL(k_pre,  dim3(417), dim3(256), 0, stream,
                       Wq, Wk, Wv, W1, ca, cp, lens, Mxf, W1f, ord, zar, tks, out);
    hipLaunchKernelGGL(k_main, dim3(NN), dim3(512), 0, stream,
                       E, ht, evt, codes, lens, ca, cp, Mxf, ord, Rbf);
    hipLaunchKernelGGL(k_mlp,  dim3(NN / 16, 4), dim3(256), 0, stream,
                       demo, labels, b1, W2, b2, Rbf, W1f, zar, tks, out);
}

// Round 13
// 220.243 us; speedup vs baseline: 1.0220x; 1.0220x over previous
//
#include <hip/hip_runtime.h>
#include <hip/hip_bf16.h>
#include <math.h>
#include <stdint.h>

#define VV 20000
#define LL 128
#define DD 256
#define DEMO_ 70
#define HID_ 1024
#define NN 2048

typedef __attribute__((ext_vector_type(8))) short short8;
typedef __attribute__((ext_vector_type(4))) float f32x4;

// ---- bf16 helpers ----
__device__ __forceinline__ float bf2f(uint32_t u) {
    union { uint32_t u; float f; } c; c.u = u << 16; return c.f;
}
__device__ __forceinline__ uint32_t f2bf(float f) {
    union { float f; uint32_t u; } c; c.f = f;
    return (c.u + 0x7fffu + ((c.u >> 16) & 1u)) >> 16;   // RNE
}

// swizzled halfword offset inside a [128][256] bf16 LDS tile
__device__ __forceinline__ int sw_off(int row, int col) {
    return (row << 8) + ((((col >> 3) ^ (row & 7)) << 3) | (col & 7));
}

// ---- fused pre-kernel (R7/R10-verified) ----
__global__ __launch_bounds__(256) void k_pre(
    const float* __restrict__ Wq, const float* __restrict__ Wk,
    const float* __restrict__ Wv, const float* __restrict__ W1,
    const float* __restrict__ ca, const float* __restrict__ cp,
    const int* __restrict__ lens,
    unsigned short* __restrict__ Mxf, unsigned short* __restrict__ W1f,
    int* __restrict__ order, float* __restrict__ z,
    int* __restrict__ tickets, float* __restrict__ out)
{
    __shared__ float sm[DD];
    __shared__ float wvs[8][DD];
    __shared__ int cnt[9], off[9], cur[9];
    const int b = blockIdx.x, t = threadIdx.x;

    if (b < 256) {
        int e = b;
        sm[t] = Wq[(size_t)e * DD + t];
        __syncthreads();
        const float4* wk4 = (const float4*)(Wk + (size_t)t * DD);
        const float4* wq4 = (const float4*)sm;
        float4 acc = make_float4(0.f, 0.f, 0.f, 0.f);
        #pragma unroll 8
        for (int c = 0; c < DD / 4; ++c) {
            float4 a = wq4[c]; float4 bb = wk4[c];
            acc.x += a.x * bb.x; acc.y += a.y * bb.y;
            acc.z += a.z * bb.z; acc.w += a.w * bb.w;
        }
        float val = acc.x + acc.y + acc.z + acc.w;
        int frag = (e >> 4) * 8 + (t >> 5);
        int pos  = (((t >> 3) & 3) * 16 + (e & 15)) * 8 + (t & 7);
        Mxf[(size_t)frag * 512 + pos] = (unsigned short)f2bf(val);
    } else if (b < 384) {
        int f = b - 256, kg = f >> 2, hh = f & 3;
        #pragma unroll
        for (int r = 0; r < 8; ++r)
            wvs[r][t] = Wv[(size_t)(kg * 8 + r) * DD + t];
        __syncthreads();
        int h = hh * 256 + t;
        float acc[8];
        #pragma unroll
        for (int r = 0; r < 8; ++r) acc[r] = 0.f;
        #pragma unroll 4
        for (int n = 0; n < DD; ++n) {
            float a = W1[(size_t)(DEMO_ + n) * HID_ + h];
            #pragma unroll
            for (int r = 0; r < 8; ++r) acc[r] += wvs[r][n] * a;
        }
        #pragma unroll
        for (int r = 0; r < 8; ++r) {
            int k = DEMO_ + kg * 8 + r;
            int frag = (h >> 4) * 11 + (k >> 5);
            int pos  = (((k >> 3) & 3) * 16 + (h & 15)) * 8 + (k & 7);
            W1f[(size_t)frag * 512 + pos] = (unsigned short)f2bf(acc[r]);
        }
    } else if (b < 416) {
        int g = b - 384;
        for (int idx = g * 256 + t; idx < 96 * 1024; idx += 32 * 256) {
            int kk = idx >> 10, h = idx & 1023;
            int k = kk < DEMO_ ? kk : kk + 256;
            float val = kk < DEMO_ ? W1[(size_t)kk * HID_ + h] : 0.f;
            int frag = (h >> 4) * 11 + (k >> 5);
            int pos  = (((k >> 3) & 3) * 16 + (h & 15)) * 8 + (k & 7);
            W1f[(size_t)frag * 512 + pos] = (unsigned short)f2bf(val);
        }
    } else {
        for (int i = t; i < NN; i += 256) z[i] = 0.f;
        if (t < 128) tickets[t] = 0;
        if (t < 9) cnt[t] = 0;
        __syncthreads();
        for (int i = t; i < NN; i += 256)
            atomicAdd(&cnt[(lens[i] + 15) >> 4], 1);
        __syncthreads();
        if (t == 0) {
            int acc = 0;
            for (int k = 8; k >= 1; --k) { off[k] = acc; acc += cnt[k]; cur[k] = off[k]; }
            out[0] = ca[0] * ca[0] + cp[0] * cp[0];
        }
        __syncthreads();
        for (int i = t; i < NN; i += 256) {
            int key = (lens[i] + 15) >> 4;
            int pos = atomicAdd(&cur[key], 1);
            order[pos] = i;
        }
    }
}

// ---- kernel 2: per-sample attention+pooling. R5 shape + wpt tile-sharing ----
__global__ __launch_bounds__(512, 4) void k_main(
    const float* __restrict__ E,
    const float* __restrict__ ht,  const float* __restrict__ evt_t,
    const int* __restrict__ codes, const int* __restrict__ lens,
    const float* __restrict__ ca_p, const float* __restrict__ cp_p,
    const unsigned short* __restrict__ Mxf,
    const int* __restrict__ order,
    unsigned short* __restrict__ Rbf)
{
    __shared__ __align__(16) unsigned short emb_u[LL * DD];   // 64 KB; H overwrites in place
    __shared__ float times_s[LL];
    __shared__ int   codes_s[LL];
    __shared__ float w_s[LL];
    __shared__ float apart[8][LL];      // zero-inited; summed over all 8
    __shared__ float rp_part[8][DD];    // zero-inited; summed over all 8
    __shared__ float asum[LL];
    __shared__ float psum[8][16];       // partial rowsums exchange

    const int n = order[blockIdx.x];
    const int tid = threadIdx.x, wv = tid >> 6, ln = tid & 63;
    const int q = ln >> 4, m = ln & 15;
    const int len = lens[n];
    const int it_n = (len + 15) >> 4;
    const float ca = ca_p[0], cp = cp_p[0];
    const float evt = evt_t[n];

    // waves-per-tile: it_n 1->8, 2->4, 3/4->2, >=5->1 (all powers of 2)
    const int wsh = (it_n <= 1) ? 3 : (it_n == 2) ? 2 : (it_n <= 4) ? 1 : 0;
    const int wpt = 1 << wsh;
    const int tt = wv >> wsh, ss = wv & (wpt - 1);
    const bool act = tt < it_n;

    // ---- preload B-frags for phase B (in flight across gather)
    short8 bB[2][8];
    #pragma unroll
    for (int nt = 0; nt < 2; ++nt)
        #pragma unroll
        for (int kk = 0; kk < 8; ++kk)
            bB[nt][kk] = *(const short8*)(Mxf + (size_t)((wv * 2 + nt) * 8 + kk) * 512 + ln * 8);

    // ---- zero accumulation buffers (summed over all 8 wave slots later)
    ((float*)apart)[tid]          = 0.f;
    ((float*)apart)[tid + 512]    = 0.f;
    ((float*)rp_part)[tid]        = 0.f;
    ((float*)rp_part)[tid + 512]  = 0.f;
    ((float*)rp_part)[tid + 1024] = 0.f;
    ((float*)rp_part)[tid + 1536] = 0.f;

    // ---- stage times/codes (waves 0-1); pooling weights from global (wave 0)
    if (tid < LL) {
        bool v = tid < len;
        times_s[tid] = v ? ht[(size_t)n * LL + tid] : 0.f;
        codes_s[tid] = v ? codes[(size_t)n * LL + tid] : 0;
    }
    if (wv == 0) {
        float t0 = (ln      < len) ? ht[(size_t)n * LL + ln]      : 0.f;
        float t1 = (ln + 64 < len) ? ht[(size_t)n * LL + ln + 64] : 0.f;
        float e0 = (ln      < len) ? __expf(cp * (t0 - evt)) : 0.f;
        float e1 = (ln + 64 < len) ? __expf(cp * (t1 - evt)) : 0.f;
        float smm = e0 + e1;
        for (int o = 32; o; o >>= 1) smm += __shfl_xor(smm, o, 64);
        float inv = 1.f / smm;
        if (ln      < len) w_s[ln]      = e0 * inv;
        if (ln + 64 < len) w_s[ln + 64] = e1 * inv;
    }
    __syncthreads();

    // ---- gather E rows -> swizzled bf16 LDS, 4 rows in flight per wave
    for (int l0 = wv; l0 < len; l0 += 32) {
        float4 v[4];
        #pragma unroll
        for (int u = 0; u < 4; ++u) {
            int l = l0 + u * 8;
            if (l < len)
                v[u] = ((const float4*)(E + (size_t)codes_s[l] * DD))[ln];
        }
        #pragma unroll
        for (int u = 0; u < 4; ++u) {
            int l = l0 + u * 8;
            if (l < len)
                *(uint2*)&emb_u[sw_off(l, 4 * ln)] =
                    make_uint2(f2bf(v[u].x) | (f2bf(v[u].y) << 16),
                               f2bf(v[u].z) | (f2bf(v[u].w) << 16));
        }
    }
    __syncthreads();

    // ---- phase B: H = emb @ Mx^T, overwriting emb tile-by-tile
    short8 aC[8];                        // cached A-frags for row tile tt
    for (int it = 0; it < it_n; ++it) {
        f32x4 h0 = (f32x4)0.f, h1 = (f32x4)0.f;
        #pragma unroll
        for (int kk = 0; kk < 8; ++kk) {
            short8 af = *(const short8*)&emb_u[sw_off(it * 16 + m, kk * 32 + q * 8)];
            if (it == tt) aC[kk] = af;   // wave-uniform
            h0 = __builtin_amdgcn_mfma_f32_16x16x32_bf16(af, bB[0][kk], h0, 0, 0, 0);
            h1 = __builtin_amdgcn_mfma_f32_16x16x32_bf16(af, bB[1][kk], h1, 0, 0, 0);
        }
        __syncthreads();                 // all waves done reading emb tile it
        #pragma unroll
        for (int r = 0; r < 4; ++r) {
            int row = it * 16 + q * 4 + r;
            emb_u[sw_off(row, wv * 32 + m)]      = (unsigned short)f2bf(h0[r]);
            emb_u[sw_off(row, wv * 32 + 16 + m)] = (unsigned short)f2bf(h1[r]);
        }
    }
    __syncthreads();                     // H fully materialized

    // ---- phase C: wpt waves share row tile tt; wave ss takes jt = ss, ss+wpt, ...
    f32x4 sac[8];
    #pragma unroll
    for (int j2 = 0; j2 < 8; ++j2) sac[j2] = (f32x4)0.f;
    int i_base = tt * 16 + q * 4;
    float ti[4]; bool vR[4]; float rowsum[4];
    #pragma unroll
    for (int r = 0; r < 4; ++r) rowsum[r] = 0.f;

    if (act) {
        #pragma unroll
        for (int j2 = 0; j2 < 8; ++j2) {
            int jt = ss + j2 * wpt;
            if (jt < it_n) {             // wave-uniform branch
                #pragma unroll
                for (int kk = 0; kk < 8; ++kk) {
                    short8 bH = *(const short8*)&emb_u[sw_off(jt * 16 + m, kk * 32 + q * 8)];
                    sac[j2] = __builtin_amdgcn_mfma_f32_16x16x32_bf16(aC[kk], bH, sac[j2], 0, 0, 0);
                }
            }
        }
        #pragma unroll
        for (int r = 0; r < 4; ++r) {
            vR[r] = (i_base + r) < len;
            ti[r] = times_s[i_base + r];
        }
        #pragma unroll
        for (int j2 = 0; j2 < 8; ++j2) {
            int jt = ss + j2 * wpt;
            if (jt < it_n) {
                int jcol = jt * 16 + m;
                bool vC = jcol < len;
                float tj = times_s[jcol];
                #pragma unroll
                for (int r = 0; r < 4; ++r) {
                    float arg = sac[j2][r] * 0.0625f - ca * fabsf(ti[r] - tj);
                    float p = (vR[r] && vC) ? __expf(arg) : 0.f;
                    sac[j2][r] = p;
                    rowsum[r] += p;
                }
            }
        }
        #pragma unroll
        for (int r = 0; r < 4; ++r) {
            float s = rowsum[r];
            s += __shfl_xor(s, 1, 64); s += __shfl_xor(s, 2, 64);
            s += __shfl_xor(s, 4, 64); s += __shfl_xor(s, 8, 64);
            rowsum[r] = s;
        }
        if (m == 0) {                    // partial rowsums -> psum
            #pragma unroll
            for (int r = 0; r < 4; ++r) psum[wv][q * 4 + r] = rowsum[r];
        }
    }
    __syncthreads();

    if (act) {
        float sc[4];
        #pragma unroll
        for (int r = 0; r < 4; ++r) {
            float tot = 0.f;
            for (int s2 = 0; s2 < wpt; ++s2) tot += psum[tt * wpt + s2][q * 4 + r];
            sc[r] = (vR[r] && tot > 0.f) ? w_s[i_base + r] / tot : 0.f;
        }
        #pragma unroll
        for (int j2 = 0; j2 < 8; ++j2) {
            int jt = ss + j2 * wpt;
            if (jt < it_n) {
                float v = sc[0] * sac[j2][0] + sc[1] * sac[j2][1]
                        + sc[2] * sac[j2][2] + sc[3] * sac[j2][3];
                v += __shfl_xor(v, 16, 64);
                v += __shfl_xor(v, 32, 64);
                if (q == 0) apart[wv][jt * 16 + m] = v;
            }
        }
    }
    __syncthreads();

    if (tid < LL) {
        float s = 0.f;
        #pragma unroll
        for (int r = 0; r < 8; ++r) s += apart[r][tid];
        asum[tid] = s;
    }
    __syncthreads();

    // ---- phase D: rp from aC registers; wave ss takes contiguous kk range
    if (act) {
        float aw = asum[tt * 16 + m];
        int kcnt = 8 >> wsh;             // kk per wave
        int kk0 = ss * kcnt, kk1 = kk0 + kcnt;
        #pragma unroll
        for (int kk = 0; kk < 8; ++kk) {
            if (kk >= kk0 && kk < kk1) { // wave-uniform branch
                float v[8];
                #pragma unroll
                for (int j = 0; j < 8; ++j)
                    v[j] = aw * bf2f((uint32_t)(unsigned short)aC[kk][j]);
                #pragma unroll
                for (int o = 1; o <= 8; o <<= 1)
                    #pragma unroll
                    for (int j = 0; j < 8; ++j)
                        v[j] += __shfl_xor(v[j], o, 64);
                if (m < 8)
                    rp_part[wv][kk * 32 + q * 8 + m] = v[m];
            }
        }
    }
    __syncthreads();
    if (tid < DD) {
        float r = 0.f;
        #pragma unroll
        for (int t2 = 0; t2 < 8; ++t2) r += rp_part[t2][tid];
        Rbf[(size_t)n * DD + tid] = (unsigned short)f2bf(r);
    }
}

// ---- kernel 3: batched MLP partial-z + last-block BCE (R10-verified) ----
__global__ __launch_bounds__(256) void k_mlp(
    const float* __restrict__ demo, const float* __restrict__ labels,
    const float* __restrict__ b1,   const float* __restrict__ W2,
    const float* __restrict__ b2,
    const unsigned short* __restrict__ Rbf,
    const unsigned short* __restrict__ W1f,
    float* __restrict__ z, int* __restrict__ tickets,
    float* __restrict__ out)
{
    __shared__ __align__(16) unsigned short xs[16][360];
    __shared__ float W2s[256];
    __shared__ float b1s[256];
    __shared__ float wred[4][16];
    __shared__ int   lastflag;

    const int tid = threadIdx.x, wv = tid >> 6, ln = tid & 63;
    const int q = ln >> 4, m = ln & 15;
    const int sg = blockIdx.x;
    const int s0 = sg * 16;
    const int by = blockIdx.y;
    const int hbase = by * 256;

    W2s[tid] = W2[hbase + tid];
    b1s[tid] = b1[hbase + tid];
    {
        int sh = tid >> 6, lane = tid & 63;
        for (int s = sh; s < 16; s += 4) {
            int n_s = s0 + s;
            const uint32_t* rsrc = (const uint32_t*)(Rbf + (size_t)n_s * DD);
            ((uint32_t*)&xs[s][DEMO_])[lane]      = rsrc[lane];
            ((uint32_t*)&xs[s][DEMO_])[lane + 64] = rsrc[lane + 64];
            if (lane < 35) {
                float2 d = ((const float2*)(demo + (size_t)n_s * DEMO_))[lane];
                xs[s][2 * lane]     = (unsigned short)f2bf(d.x);
                xs[s][2 * lane + 1] = (unsigned short)f2bf(d.y);
            }
            if (lane < 17) ((uint32_t*)&xs[s][326])[lane] = 0;
        }
    }
    __syncthreads();

    f32x4 cacc[4];
    #pragma unroll
    for (int ntl = 0; ntl < 4; ++ntl) cacc[ntl] = (f32x4)0.f;

    for (int kk = 0; kk < 11; ++kk) {
        short8 af = *(const short8*)&xs[m][kk * 32 + q * 8];
        #pragma unroll
        for (int ntl = 0; ntl < 4; ++ntl) {
            int frag = (by * 16 + wv * 4 + ntl) * 11 + kk;
            short8 bfd = *(const short8*)(W1f + (size_t)frag * 512 + ln * 8);
            cacc[ntl] = __builtin_amdgcn_mfma_f32_16x16x32_bf16(af, bfd, cacc[ntl], 0, 0, 0);
        }
    }

    float ls0 = 0.f, ls1 = 0.f, ls2 = 0.f, ls3 = 0.f;
    #pragma unroll
    for (int ntl = 0; ntl < 4; ++ntl) {
        int hl = wv * 64 + ntl * 16 + m;
        float bb = b1s[hl], w2v = W2s[hl];
        ls0 += fmaxf(cacc[ntl][0] + bb, 0.f) * w2v;
        ls1 += fmaxf(cacc[ntl][1] + bb, 0.f) * w2v;
        ls2 += fmaxf(cacc[ntl][2] + bb, 0.f) * w2v;
        ls3 += fmaxf(cacc[ntl][3] + bb, 0.f) * w2v;
    }
    #pragma unroll
    for (int o = 1; o <= 8; o <<= 1) {
        ls0 += __shfl_xor(ls0, o, 64); ls1 += __shfl_xor(ls1, o, 64);
        ls2 += __shfl_xor(ls2, o, 64); ls3 += __shfl_xor(ls3, o, 64);
    }
    if (m == 0) {
        wred[wv][q * 4 + 0] = ls0; wred[wv][q * 4 + 1] = ls1;
        wred[wv][q * 4 + 2] = ls2; wred[wv][q * 4 + 3] = ls3;
    }
    __syncthreads();
    if (tid < 16)
        atomicAdd(&z[s0 + tid], wred[0][tid] + wred[1][tid] + wred[2][tid] + wred[3][tid]);
    __syncthreads();

    if (tid == 0) {
        __threadfence();
        int ticket = atomicAdd(&tickets[sg], 1);
        lastflag = (ticket == 3);
    }
    __syncthreads();
    if (lastflag && wv == 0) {
        float loss = 0.f;
        if (ln < 16) {
            float zz = atomicAdd(&z[s0 + ln], 0.f) + b2[0];   // device-scope read
            float y = labels[s0 + ln];
            float lg = log1pf(__expf(-fabsf(zz)));
            loss = 2.f * y * (fmaxf(-zz, 0.f) + lg)
                 + (1.f - y) * (fmaxf(zz, 0.f) + lg);
        }
        #pragma unroll
        for (int o = 1; o <= 8; o <<= 1) loss += __shfl_xor(loss, o, 64);
        if (ln == 0) atomicAdd(out, loss * (1.f / (float)NN));
    }
}

extern "C" void kernel_launch(void* const* d_in, const int* in_sizes, int n_in,
                              void* d_out, int out_size, void* d_ws, size_t ws_size,
                              hipStream_t stream) {
    const float* E      = (const float*)d_in[0];
    const float* Wq     = (const float*)d_in[1];
    const float* Wk     = (const float*)d_in[2];
    const float* Wv     = (const float*)d_in[3];
    const float* ca     = (const float*)d_in[4];
    const float* cp     = (const float*)d_in[5];
    const float* W1     = (const float*)d_in[6];
    const float* b1     = (const float*)d_in[7];
    const float* W2     = (const float*)d_in[8];
    const float* b2     = (const float*)d_in[9];
    const float* demo   = (const float*)d_in[10];
    const float* ht     = (const float*)d_in[11];
    const float* evt    = (const float*)d_in[12];
    const float* labels = (const float*)d_in[13];
    const int*   codes  = (const int*)d_in[14];
    const int*   lens   = (const int*)d_in[15];
    float* out = (float*)d_out;

    unsigned short* Mxf = (unsigned short*)d_ws;                           // 128 KB
    unsigned short* W1f = (unsigned short*)((char*)d_ws + 131072);         // 704 KB
    unsigned short* Rbf = (unsigned short*)((char*)d_ws + 851968);         // 1 MB
    float*          zar = (float*)((char*)d_ws + 1900544);                 // 8 KB
    int*            ord = (int*)((char*)d_ws + 1908736);                   // 8 KB
    int*            tks = (int*)((char*)d_ws + 1916928);                   // 512 B

    hipLaunchKernelGGL(k_pre,  dim3(417), dim3(256), 0, stream,
                       Wq, Wk, Wv, W1, ca, cp, lens, Mxf, W1f, ord, zar, tks, out);
    hipLaunchKernelGGL(k_main, dim3(NN), dim3(512), 0, stream,
                       E, ht, evt, codes, lens, ca, cp, Mxf, ord, Rbf);
    hipLaunchKernelGGL(k_mlp,  dim3(NN / 16, 4), dim3(256), 0, stream,
                       demo, labels, b1, W2, b2, Rbf, W1f, zar, tks, out);
}